// Round 7
// baseline (499.196 us; speedup 1.0000x reference)
//
#include <hip/hip_runtime.h>
#include <hip/hip_bf16.h>
#include <math.h>
#include <stdint.h>

#define DIM 2048
#define NH 16
#define HD 128
#define BB 8
#define TT 1024
#define NROW (BB*TT)        // 8192
#define QKVD (DIM + 2*HD)   // 2304

typedef unsigned short u16;
typedef unsigned int u32;
typedef float f32x4 __attribute__((ext_vector_type(4)));
typedef u32 u32x4 __attribute__((ext_vector_type(4)));
typedef __bf16 bf16x8 __attribute__((ext_vector_type(8)));

// 1/sqrt(128) * log2(e): Q pre-scaled so softmax runs in exp2 domain
#define QSCALE_LOG2E (0.08838834764831845f * 1.4426950408889634f)

__device__ inline u16 f2bf(float f) {
  u32 u = __builtin_bit_cast(u32, f);
  u += 0x7FFF + ((u >> 16) & 1);   // round-to-nearest-even
  return (u16)(u >> 16);
}

__device__ inline u32 cvt_pk_bf16(float lo, float hi) {
  u32 d;
  asm("v_cvt_pk_bf16_f32 %0, %1, %2" : "=v"(d) : "v"(lo), "v"(hi));
  return d;
}

__device__ inline void gload_lds16(const void* g, void* l) {
  __builtin_amdgcn_global_load_lds(
      (const __attribute__((address_space(1))) void*)g,
      (__attribute__((address_space(3))) void*)l,
      16, 0, 0);
}

// ---------------- elementwise f32 -> bf16 ----------------
__global__ void cvt_f32_bf16(const float* __restrict__ in, u16* __restrict__ out, int n4) {
  int i = blockIdx.x * blockDim.x + threadIdx.x;
  int st = gridDim.x * blockDim.x;
  for (; i < n4; i += st) {
    float4 v = reinterpret_cast<const float4*>(in)[i];
    ushort4 o;
    o.x = f2bf(v.x); o.y = f2bf(v.y); o.z = f2bf(v.z); o.w = f2bf(v.w);
    reinterpret_cast<ushort4*>(out)[i] = o;
  }
}

// ---------------- NT GEMM: C[n,m] = sum_k A[n,k]*B[m,k] + bias[m] ----------------
// (unchanged from R6 — proven: ~890 TF each)
template<bool OUT_BF16, bool WRITE_VT>
__global__ __launch_bounds__(256, 3) void gemm_nt(
    const u16* __restrict__ A, const u16* __restrict__ Bm,
    const float* __restrict__ bias, void* __restrict__ Cout,
    u16* __restrict__ vT, int K, int Mcols)
{
  __shared__ __align__(16) u16 sbuf[3][8192];   // [buf]{A:4096, B:4096} = 16KB x3
  const int tid = threadIdx.x;
  const int w = tid >> 6, l = tid & 63;
  const int wm = w >> 1, wn = w & 1;
  const int rl = l & 15, gl = l >> 4;
  const int rowBase = blockIdx.x * 128;
  const int colBase = blockIdx.y * 128;

  const int rT = tid >> 2;
  const int t4 = tid & 3;
  const int cswE = (t4 * 8) ^ (((rT >> 1) & 3) << 3);   // u16 element offset in row
  const u16* aSrc0 = A  + (size_t)(rowBase + rT) * K + cswE;
  const u16* bSrc0 = Bm + (size_t)(colBase + rT) * K + cswE;
  const size_t rowSk = (size_t)64 * K;

  auto STAGE = [&](int kt) {
    u16* base = &sbuf[kt % 3][0];
    const int k0 = kt * 32;
    gload_lds16(aSrc0 + k0,         base + (size_t)tid * 8);
    gload_lds16(aSrc0 + rowSk + k0, base + 2048 + (size_t)tid * 8);
    gload_lds16(bSrc0 + k0,         base + 4096 + (size_t)tid * 8);
    gload_lds16(bSrc0 + rowSk + k0, base + 4096 + 2048 + (size_t)tid * 8);
  };

  int aOff[4], bOff[4];
#pragma unroll
  for (int f = 0; f < 4; ++f) {
    int ra = wm * 64 + f * 16 + rl;
    aOff[f] = ra * 32 + ((gl * 8) ^ (((ra >> 1) & 3) << 3));
    int rb = wn * 64 + f * 16 + rl;
    bOff[f] = 4096 + rb * 32 + ((gl * 8) ^ (((rb >> 1) & 3) << 3));
  }

  f32x4 acc[4][4] = {};

#define GEMM_BODY(KT)                                                          \
  {                                                                            \
    __builtin_amdgcn_sched_barrier(0);                                         \
    __builtin_amdgcn_s_barrier();                                              \
    const u16* base = &sbuf[(KT) % 3][0];                                      \
    bf16x8 af[4], bf[4];                                                       \
    _Pragma("unroll")                                                          \
    for (int f = 0; f < 4; ++f) af[f] = *(const bf16x8*)(base + aOff[f]);      \
    _Pragma("unroll")                                                          \
    for (int f = 0; f < 4; ++f) bf[f] = *(const bf16x8*)(base + bOff[f]);      \
    asm volatile("s_waitcnt lgkmcnt(0)" ::: "memory");                         \
    __builtin_amdgcn_sched_barrier(0);                                         \
    __builtin_amdgcn_s_barrier();                                              \
    __builtin_amdgcn_s_setprio(1);                                             \
    _Pragma("unroll")                                                          \
    for (int fm = 0; fm < 4; ++fm)                                             \
      _Pragma("unroll")                                                        \
      for (int fn = 0; fn < 4; ++fn)                                           \
        acc[fm][fn] = __builtin_amdgcn_mfma_f32_16x16x32_bf16(af[fm], bf[fn],  \
                                                              acc[fm][fn], 0, 0, 0); \
    __builtin_amdgcn_s_setprio(0);                                             \
  }

  const int NT = K >> 5;          // 64 for K=2048
  STAGE(0);
  STAGE(1);

  for (int kt = 0; kt < NT - 2; ++kt) {
    STAGE(kt + 2);
    asm volatile("s_waitcnt vmcnt(8)" ::: "memory");   // 12 in flight -> tile kt done
    GEMM_BODY(kt);
  }
  asm volatile("s_waitcnt vmcnt(4)" ::: "memory");
  GEMM_BODY(NT - 2);
  asm volatile("s_waitcnt vmcnt(0)" ::: "memory");
  GEMM_BODY(NT - 1);
#undef GEMM_BODY

  float bv[4];
#pragma unroll
  for (int fn = 0; fn < 4; ++fn) bv[fn] = bias[colBase + wn*64 + fn*16 + rl];

#pragma unroll
  for (int fm = 0; fm < 4; ++fm) {
#pragma unroll
    for (int fn = 0; fn < 4; ++fn) {
      const int col = colBase + wn*64 + fn*16 + rl;
#pragma unroll
      for (int r = 0; r < 4; ++r) {
        const int row = rowBase + wm*64 + fm*16 + gl*4 + r;
        float v = acc[fm][fn][r] + bv[fn];
        if (WRITE_VT && col >= DIM + HD) {   // V columns: also store V^T[b][d][t]
          int d = col - (DIM + HD);
          int b = row >> 10, t = row & 1023;
          vT[((size_t)(b*HD + d) << 10) + t] = f2bf(v);
        }
        float vs = (WRITE_VT && col < DIM) ? v * QSCALE_LOG2E : v;  // pre-scale Q
        if (OUT_BF16) ((u16*)Cout)[(size_t)row*Mcols + col] = f2bf(vs);
        else          ((float*)Cout)[(size_t)row*Mcols + col] = vs;
      }
    }
  }
}

// ---------------- causal MQA flash attention ----------------
// grid: (T/128, B*H). 8 waves x 16 q-rows = 128 q-rows/block. KV tile = 32, dbuf.
// LDS = 2 x { K: 32s x 128d (8KB, slot16 ^= s&7) | V^T: 128d x 32s (8KB, slot16 ^= (d>>1)&3) }
// = 32KB -> 4 blocks/CU at <=64 VGPR -> all 1024 blocks resident in ONE tranche.
__global__ __launch_bounds__(512, 8) void mqa_attn(
    const u16* __restrict__ qkv, const u16* __restrict__ vT,
    u16* __restrict__ attout)
{
  __shared__ char lds[32768];

  const int tid = threadIdx.x;
  const int wid = tid >> 6, l = tid & 63;
  const int rl = l & 15, gl = l >> 4;
  const int qb = (int)gridDim.x - 1 - (int)blockIdx.x;  // heavy blocks dispatch first
  const int b = blockIdx.y >> 4, h = blockIdx.y & 15;
  const int qrow0 = qb*128 + wid*16;
  const int diag = qrow0 >> 5;     // this wave's diagonal KV-tile index (32-wide tiles)
  const int itmax = 4*qb + 3;

  const u16* kbase = qkv + (size_t)b*TT*QKVD + DIM;
  const u16* vbase = vT + ((size_t)b*HD << 10);

  // per-thread staging geometry (constant)
  const int ks = tid >> 4;            // K: s-row, 16B-chunk tid&15
  const int kchunk = (tid & 15) ^ (ks & 7);
  const int vd = tid >> 2;            // V: d-row, 16B-chunk tid&3
  const int vchunk = (tid & 3) ^ ((vd >> 1) & 3);

  // stage one 32-wide KV tile: 2 x gload_lds16 per thread (K 8KB + V 8KB)
  auto STAGE = [&](int buf, int s0) {
    char* base = lds + buf*16384;
    gload_lds16(kbase + (size_t)(s0 + ks)*QKVD + kchunk*8, base + tid*16);
    gload_lds16(vbase + ((size_t)vd << 10) + s0 + vchunk*8, base + 8192 + tid*16);
  };

  STAGE(0, 0);
  asm volatile("" ::: "memory");

  // Q fragments (B-operand: col=t=rl, k=d); Q already scaled by 1/sqrt(hd)*log2e
  bf16x8 qf[4];
  {
    const u16* qp = qkv + (size_t)(b*TT + qrow0 + rl)*QKVD + h*HD + gl*8;
#pragma unroll
    for (int kk = 0; kk < 4; ++kk) qf[kk] = *(const bf16x8*)(qp + kk*32);
  }

  f32x4 accO[8] = {};
  float mrow = -INFINITY, lrow = 0.f;
  const int tg = qrow0 + rl;                         // this lane's q-row
  const int addrA = (((gl & 1) * 2) * 16 + rl) * 4;  // bpermute byte addrs
  const int addrB = addrA + 64;
  const bool hiSel = (gl >= 2);

  for (int it = 0; it <= itmax; ++it) {
    if (it < itmax) {
      STAGE((it + 1) & 1, (it + 1) << 5);
      asm volatile("s_waitcnt vmcnt(2)" ::: "memory");  // current tile done, next in flight
    } else {
      asm volatile("s_waitcnt vmcnt(0)" ::: "memory");
    }
    __builtin_amdgcn_s_barrier();

    if (it <= diag) {   // wave-uniform: skip fully-future tiles (still stage+barrier)
      const char* kl = lds + (it & 1)*16384;
      const char* vl = kl + 8192;
      const int s0 = it << 5;

      // S^T = mfma(K, Q): sc[fs][r] = S^T[s = s0 + fs*16 + gl*4 + r][t = rl], exp2 domain
      f32x4 sc[2] = {};
      __builtin_amdgcn_s_setprio(1);
#pragma unroll
      for (int fs = 0; fs < 2; ++fs) {
        const int s = fs*16 + rl;
#pragma unroll
        for (int kkd = 0; kkd < 4; ++kkd) {
          bf16x8 kf = *(const bf16x8*)(kl + ((s*256 + kkd*64 + gl*16) ^ ((s & 7) << 4)));
          sc[fs] = __builtin_amdgcn_mfma_f32_16x16x32_bf16(kf, qf[kkd], sc[fs], 0, 0, 0);
        }
      }
      __builtin_amdgcn_s_setprio(0);

      // causal mask only on the diagonal tile (wave-uniform branch)
      if (it == diag) {
#pragma unroll
        for (int fs = 0; fs < 2; ++fs)
#pragma unroll
          for (int r = 0; r < 4; ++r) {
            int sg = s0 + fs*16 + gl*4 + r;
            if (sg > tg) sc[fs][r] = -INFINITY;
          }
      }

      // tile max (8 values + 2 shfl)
      float mx = fmaxf(fmaxf(fmaxf(sc[0][0], sc[0][1]), fmaxf(sc[0][2], sc[0][3])),
                       fmaxf(fmaxf(sc[1][0], sc[1][1]), fmaxf(sc[1][2], sc[1][3])));
      mx = fmaxf(mx, __shfl_xor(mx, 16));
      mx = fmaxf(mx, __shfl_xor(mx, 32));

      // defer-max: rescale only if max grew by > 8 (exp2 domain -> P <= 256)
      if (!__all(mx <= mrow + 8.f)) {
        float mnew = fmaxf(mrow, mx);
        float rr = __builtin_amdgcn_exp2f(mrow - mnew);
#pragma unroll
        for (int fd = 0; fd < 8; ++fd)
#pragma unroll
          for (int r = 0; r < 4; ++r) accO[fd][r] *= rr;
        lrow *= rr;
        mrow = mnew;
      }

      float ps = 0.f;
#pragma unroll
      for (int fs = 0; fs < 2; ++fs)
#pragma unroll
        for (int r = 0; r < 4; ++r) {
          float p = __builtin_amdgcn_exp2f(sc[fs][r] - mrow);
          sc[fs][r] = p;
          ps += p;
        }
      ps += __shfl_xor(ps, 16);
      ps += __shfl_xor(ps, 32);
      lrow += ps;

      // pack P^T to bf16 pairs, redistribute into the PV B-fragment via bpermute
      u32 pw[2][2];
#pragma unroll
      for (int fs = 0; fs < 2; ++fs) {
        pw[fs][0] = cvt_pk_bf16(sc[fs][0], sc[fs][1]);
        pw[fs][1] = cvt_pk_bf16(sc[fs][2], sc[fs][3]);
      }
      u32x4 bw;
#pragma unroll
      for (int w = 0; w < 4; ++w) {
        int addr = (w < 2) ? addrA : addrB;
        u32 lo = __builtin_amdgcn_ds_bpermute(addr, (int)pw[0][w & 1]);
        u32 hi = __builtin_amdgcn_ds_bpermute(addr, (int)pw[1][w & 1]);
        bw[w] = hiSel ? hi : lo;
      }
      bf16x8 pb = __builtin_bit_cast(bf16x8, bw);

      // O^T += V^T * P^T : accO[fd][r] = O^T[d = fd*16 + gl*4 + r][t = rl]
      __builtin_amdgcn_s_setprio(1);
#pragma unroll
      for (int fd = 0; fd < 8; ++fd) {
        const int d = fd*16 + rl;
        bf16x8 vf = *(const bf16x8*)(vl + d*64 + ((gl ^ ((d >> 1) & 3)) << 4));
        accO[fd] = __builtin_amdgcn_mfma_f32_16x16x32_bf16(vf, pb, accO[fd], 0, 0, 0);
      }
      __builtin_amdgcn_s_setprio(0);
    }

    __builtin_amdgcn_s_barrier();   // all waves done reading buf[it&1] before overwrite
  }

  const float inv = 1.0f / lrow;
  u16* outp = attout + (size_t)(b*TT + tg)*DIM + h*HD;
#pragma unroll
  for (int fd = 0; fd < 8; ++fd) {
    ushort4 o;
    o.x = f2bf(accO[fd][0] * inv);
    o.y = f2bf(accO[fd][1] * inv);
    o.z = f2bf(accO[fd][2] * inv);
    o.w = f2bf(accO[fd][3] * inv);
    *(ushort4*)(outp + fd*16 + gl*4) = o;
  }
}

// ---------------- launch ----------------
extern "C" void kernel_launch(void* const* d_in, const int* in_sizes, int n_in,
                              void* d_out, int out_size, void* d_ws, size_t ws_size,
                              hipStream_t stream) {
  const float* x    = (const float*)d_in[0];
  const float* Wqkv = (const float*)d_in[1];
  const float* bqkv = (const float*)d_in[2];
  const float* Wout = (const float*)d_in[3];
  const float* bout = (const float*)d_in[4];

  char* ws = (char*)d_ws;
  u16* xb    = (u16*)(ws);
  u16* wqb   = (u16*)(ws + 33554432);
  u16* qkvb  = (u16*)(ws + 33554432 + 9437184);
  u16* vtb   = (u16*)(ws + 33554432 + 9437184 + 37748736);
  u16* attb  = xb;     // x_bf16 dead after GEMM1
  u16* woutb = wqb;    // Wqkv_bf16 dead after GEMM1

  cvt_f32_bf16<<<2048, 256, 0, stream>>>(x,    xb,  NROW*DIM/4);
  cvt_f32_bf16<<<2048, 256, 0, stream>>>(Wqkv, wqb, QKVD*DIM/4);

  dim3 g1(NROW/128, QKVD/128);
  gemm_nt<true, true><<<g1, 256, 0, stream>>>(xb, wqb, bqkv, qkvb, vtb, DIM, QKVD);

  cvt_f32_bf16<<<2048, 256, 0, stream>>>(Wout, woutb, DIM*DIM/4);

  dim3 ga(TT/128, BB*NH);
  mqa_attn<<<ga, 512, 0, stream>>>(qkvb, vtb, attb);

  dim3 g2(NROW/128, DIM/128);
  gemm_nt<false, false><<<g2, 256, 0, stream>>>(attb, woutb, bout, d_out, nullptr, DIM, DIM);
}

// Round 8
// 328.407 us; speedup vs baseline: 1.5201x; 1.5201x over previous
//
#include <hip/hip_runtime.h>
#include <hip/hip_bf16.h>
#include <math.h>
#include <stdint.h>

#define DIM 2048
#define NH 16
#define HD 128
#define BB 8
#define TT 1024
#define NROW (BB*TT)        // 8192
#define QKVD (DIM + 2*HD)   // 2304

typedef unsigned short u16;
typedef unsigned int u32;
typedef float f32x4 __attribute__((ext_vector_type(4)));
typedef u32 u32x4 __attribute__((ext_vector_type(4)));
typedef __bf16 bf16x8 __attribute__((ext_vector_type(8)));

// 1/sqrt(128) * log2(e): Q pre-scaled so softmax runs in exp2 domain
#define QSCALE_LOG2E (0.08838834764831845f * 1.4426950408889634f)

__device__ inline u16 f2bf(float f) {
  u32 u = __builtin_bit_cast(u32, f);
  u += 0x7FFF + ((u >> 16) & 1);   // round-to-nearest-even
  return (u16)(u >> 16);
}

__device__ inline u32 cvt_pk_bf16(float lo, float hi) {
  u32 d;
  asm("v_cvt_pk_bf16_f32 %0, %1, %2" : "=v"(d) : "v"(lo), "v"(hi));
  return d;
}

__device__ inline void gload_lds16(const void* g, void* l) {
  __builtin_amdgcn_global_load_lds(
      (const __attribute__((address_space(1))) void*)g,
      (__attribute__((address_space(3))) void*)l,
      16, 0, 0);
}

// ---------------- elementwise f32 -> bf16 ----------------
__global__ void cvt_f32_bf16(const float* __restrict__ in, u16* __restrict__ out, int n4) {
  int i = blockIdx.x * blockDim.x + threadIdx.x;
  int st = gridDim.x * blockDim.x;
  for (; i < n4; i += st) {
    float4 v = reinterpret_cast<const float4*>(in)[i];
    ushort4 o;
    o.x = f2bf(v.x); o.y = f2bf(v.y); o.z = f2bf(v.z); o.w = f2bf(v.w);
    reinterpret_cast<ushort4*>(out)[i] = o;
  }
}

// ---------------- NT GEMM: C[n,m] = sum_k A[n,k]*B[m,k] + bias[m] ----------------
// (unchanged from R6 — proven: ~890 TF each)
template<bool OUT_BF16, bool WRITE_VT>
__global__ __launch_bounds__(256, 3) void gemm_nt(
    const u16* __restrict__ A, const u16* __restrict__ Bm,
    const float* __restrict__ bias, void* __restrict__ Cout,
    u16* __restrict__ vT, int K, int Mcols)
{
  __shared__ __align__(16) u16 sbuf[3][8192];   // [buf]{A:4096, B:4096} = 16KB x3
  const int tid = threadIdx.x;
  const int w = tid >> 6, l = tid & 63;
  const int wm = w >> 1, wn = w & 1;
  const int rl = l & 15, gl = l >> 4;
  const int rowBase = blockIdx.x * 128;
  const int colBase = blockIdx.y * 128;

  const int rT = tid >> 2;
  const int t4 = tid & 3;
  const int cswE = (t4 * 8) ^ (((rT >> 1) & 3) << 3);   // u16 element offset in row
  const u16* aSrc0 = A  + (size_t)(rowBase + rT) * K + cswE;
  const u16* bSrc0 = Bm + (size_t)(colBase + rT) * K + cswE;
  const size_t rowSk = (size_t)64 * K;

  auto STAGE = [&](int kt) {
    u16* base = &sbuf[kt % 3][0];
    const int k0 = kt * 32;
    gload_lds16(aSrc0 + k0,         base + (size_t)tid * 8);
    gload_lds16(aSrc0 + rowSk + k0, base + 2048 + (size_t)tid * 8);
    gload_lds16(bSrc0 + k0,         base + 4096 + (size_t)tid * 8);
    gload_lds16(bSrc0 + rowSk + k0, base + 4096 + 2048 + (size_t)tid * 8);
  };

  int aOff[4], bOff[4];
#pragma unroll
  for (int f = 0; f < 4; ++f) {
    int ra = wm * 64 + f * 16 + rl;
    aOff[f] = ra * 32 + ((gl * 8) ^ (((ra >> 1) & 3) << 3));
    int rb = wn * 64 + f * 16 + rl;
    bOff[f] = 4096 + rb * 32 + ((gl * 8) ^ (((rb >> 1) & 3) << 3));
  }

  f32x4 acc[4][4] = {};

#define GEMM_BODY(KT)                                                          \
  {                                                                            \
    __builtin_amdgcn_sched_barrier(0);                                         \
    __builtin_amdgcn_s_barrier();                                              \
    const u16* base = &sbuf[(KT) % 3][0];                                      \
    bf16x8 af[4], bf[4];                                                       \
    _Pragma("unroll")                                                          \
    for (int f = 0; f < 4; ++f) af[f] = *(const bf16x8*)(base + aOff[f]);      \
    _Pragma("unroll")                                                          \
    for (int f = 0; f < 4; ++f) bf[f] = *(const bf16x8*)(base + bOff[f]);      \
    asm volatile("s_waitcnt lgkmcnt(0)" ::: "memory");                         \
    __builtin_amdgcn_sched_barrier(0);                                         \
    __builtin_amdgcn_s_barrier();                                              \
    __builtin_amdgcn_s_setprio(1);                                             \
    _Pragma("unroll")                                                          \
    for (int fm = 0; fm < 4; ++fm)                                             \
      _Pragma("unroll")                                                        \
      for (int fn = 0; fn < 4; ++fn)                                           \
        acc[fm][fn] = __builtin_amdgcn_mfma_f32_16x16x32_bf16(af[fm], bf[fn],  \
                                                              acc[fm][fn], 0, 0, 0); \
    __builtin_amdgcn_s_setprio(0);                                             \
  }

  const int NT = K >> 5;          // 64 for K=2048
  STAGE(0);
  STAGE(1);

  for (int kt = 0; kt < NT - 2; ++kt) {
    STAGE(kt + 2);
    asm volatile("s_waitcnt vmcnt(8)" ::: "memory");   // 12 in flight -> tile kt done
    GEMM_BODY(kt);
  }
  asm volatile("s_waitcnt vmcnt(4)" ::: "memory");
  GEMM_BODY(NT - 2);
  asm volatile("s_waitcnt vmcnt(0)" ::: "memory");
  GEMM_BODY(NT - 1);
#undef GEMM_BODY

  float bv[4];
#pragma unroll
  for (int fn = 0; fn < 4; ++fn) bv[fn] = bias[colBase + wn*64 + fn*16 + rl];

#pragma unroll
  for (int fm = 0; fm < 4; ++fm) {
#pragma unroll
    for (int fn = 0; fn < 4; ++fn) {
      const int col = colBase + wn*64 + fn*16 + rl;
#pragma unroll
      for (int r = 0; r < 4; ++r) {
        const int row = rowBase + wm*64 + fm*16 + gl*4 + r;
        float v = acc[fm][fn][r] + bv[fn];
        if (WRITE_VT && col >= DIM + HD) {   // V columns: also store V^T[b][d][t]
          int d = col - (DIM + HD);
          int b = row >> 10, t = row & 1023;
          vT[((size_t)(b*HD + d) << 10) + t] = f2bf(v);
        }
        float vs = (WRITE_VT && col < DIM) ? v * QSCALE_LOG2E : v;  // pre-scale Q
        if (OUT_BF16) ((u16*)Cout)[(size_t)row*Mcols + col] = f2bf(vs);
        else          ((float*)Cout)[(size_t)row*Mcols + col] = vs;
      }
    }
  }
}

// ---------------- causal MQA flash attention ----------------
// grid: (T/64, B*H). 4 waves x 16 q-rows = 64 q-rows/block. KV tile = 32, dbuf.
// LDS = 2 x { K: 32s x 128d (8KB) | V^T: 128d x 32s (8KB) } = 32KB.
// 4 blocks/CU (16 waves) at VGPR<=128 (launch_bounds(256,4) -> NO spill; the
// R7 regression was launch_bounds(512,8) forcing a 64-VGPR cap -> accO spilled
// to scratch, FETCH 524MB). Finer blocks also smooth causal imbalance.
__global__ __launch_bounds__(256, 4) void mqa_attn(
    const u16* __restrict__ qkv, const u16* __restrict__ vT,
    u16* __restrict__ attout)
{
  __shared__ char lds[32768];

  const int tid = threadIdx.x;
  const int wid = tid >> 6, l = tid & 63;
  const int rl = l & 15, gl = l >> 4;
  const int qb = (int)gridDim.x - 1 - (int)blockIdx.x;  // heavy blocks dispatch first
  const int b = blockIdx.y >> 4, h = blockIdx.y & 15;
  const int qrow0 = qb*64 + wid*16;
  const int diag = qrow0 >> 5;     // this wave's diagonal KV-tile index (32-wide)
  const int itmax = 2*qb + 1;

  const u16* kbase = qkv + (size_t)b*TT*QKVD + DIM;
  const u16* vbase = vT + ((size_t)b*HD << 10);

  // per-thread staging geometry (256 threads, 2 chunks each for K and V).
  // K chunk c (c=tid, tid+256): row s=c>>4, chunk j=c&15, src col j^(s&7).
  //   Note (s+16)&7 == s&7, so both chunks share the swizzled column.
  // V chunk c: row d=c>>2, chunk j=c&3, src col j^((d>>1)&3); (d+64)>>1 keeps &3.
  const int ks = tid >> 4;
  const int kchunk = (tid & 15) ^ (ks & 7);
  const int vd = tid >> 2;
  const int vchunk = (tid & 3) ^ ((vd >> 1) & 3);

  auto STAGE = [&](int buf, int s0) {
    char* base = lds + buf*16384;
    const u16* ksrc = kbase + (size_t)(s0 + ks)*QKVD + kchunk*8;
    const u16* vsrc = vbase + ((size_t)vd << 10) + s0 + vchunk*8;
    gload_lds16(ksrc,                    base + tid*16);
    gload_lds16(ksrc + (size_t)16*QKVD,  base + 4096 + tid*16);
    gload_lds16(vsrc,                    base + 8192 + tid*16);
    gload_lds16(vsrc + ((size_t)64<<10), base + 8192 + 4096 + tid*16);
  };

  STAGE(0, 0);
  asm volatile("" ::: "memory");

  // Q fragments (B-operand: col=t=rl, k=d); Q already scaled by 1/sqrt(hd)*log2e
  bf16x8 qf[4];
  {
    const u16* qp = qkv + (size_t)(b*TT + qrow0 + rl)*QKVD + h*HD + gl*8;
#pragma unroll
    for (int kk = 0; kk < 4; ++kk) qf[kk] = *(const bf16x8*)(qp + kk*32);
  }

  f32x4 accO[8] = {};
  float mrow = -INFINITY, lrow = 0.f;
  const int tg = qrow0 + rl;                         // this lane's q-row
  const int addrA = (((gl & 1) * 2) * 16 + rl) * 4;  // bpermute byte addrs
  const int addrB = addrA + 64;
  const bool hiSel = (gl >= 2);

  for (int it = 0; it <= itmax; ++it) {
    if (it < itmax) {
      STAGE((it + 1) & 1, (it + 1) << 5);
      asm volatile("s_waitcnt vmcnt(4)" ::: "memory");  // current tile done, next in flight
    } else {
      asm volatile("s_waitcnt vmcnt(0)" ::: "memory");
    }
    __builtin_amdgcn_s_barrier();

    if (it <= diag) {   // wave-uniform: skip fully-future tiles (still stage+barrier)
      const char* kl = lds + (it & 1)*16384;
      const char* vl = kl + 8192;
      const int s0 = it << 5;

      // S^T = mfma(K, Q): sc[fs][r] = S^T[s = s0 + fs*16 + gl*4 + r][t = rl], exp2 domain
      f32x4 sc[2] = {};
      __builtin_amdgcn_s_setprio(1);
#pragma unroll
      for (int fs = 0; fs < 2; ++fs) {
        const int s = fs*16 + rl;
#pragma unroll
        for (int kkd = 0; kkd < 4; ++kkd) {
          bf16x8 kf = *(const bf16x8*)(kl + ((s*256 + kkd*64 + gl*16) ^ ((s & 7) << 4)));
          sc[fs] = __builtin_amdgcn_mfma_f32_16x16x32_bf16(kf, qf[kkd], sc[fs], 0, 0, 0);
        }
      }
      __builtin_amdgcn_s_setprio(0);

      // causal mask only on the diagonal tile (wave-uniform branch)
      if (it == diag) {
#pragma unroll
        for (int fs = 0; fs < 2; ++fs)
#pragma unroll
          for (int r = 0; r < 4; ++r) {
            int sg = s0 + fs*16 + gl*4 + r;
            if (sg > tg) sc[fs][r] = -INFINITY;
          }
      }

      // tile max (8 values + 2 shfl)
      float mx = fmaxf(fmaxf(fmaxf(sc[0][0], sc[0][1]), fmaxf(sc[0][2], sc[0][3])),
                       fmaxf(fmaxf(sc[1][0], sc[1][1]), fmaxf(sc[1][2], sc[1][3])));
      mx = fmaxf(mx, __shfl_xor(mx, 16));
      mx = fmaxf(mx, __shfl_xor(mx, 32));

      // defer-max: rescale only if max grew by > 8 (exp2 domain -> P <= 256)
      if (!__all(mx <= mrow + 8.f)) {
        float mnew = fmaxf(mrow, mx);
        float rr = __builtin_amdgcn_exp2f(mrow - mnew);
#pragma unroll
        for (int fd = 0; fd < 8; ++fd)
#pragma unroll
          for (int r = 0; r < 4; ++r) accO[fd][r] *= rr;
        lrow *= rr;
        mrow = mnew;
      }

      float ps = 0.f;
#pragma unroll
      for (int fs = 0; fs < 2; ++fs)
#pragma unroll
        for (int r = 0; r < 4; ++r) {
          float p = __builtin_amdgcn_exp2f(sc[fs][r] - mrow);
          sc[fs][r] = p;
          ps += p;
        }
      ps += __shfl_xor(ps, 16);
      ps += __shfl_xor(ps, 32);
      lrow += ps;

      // pack P^T to bf16 pairs, redistribute into the PV B-fragment via bpermute
      u32 pw[2][2];
#pragma unroll
      for (int fs = 0; fs < 2; ++fs) {
        pw[fs][0] = cvt_pk_bf16(sc[fs][0], sc[fs][1]);
        pw[fs][1] = cvt_pk_bf16(sc[fs][2], sc[fs][3]);
      }
      u32x4 bw;
#pragma unroll
      for (int w = 0; w < 4; ++w) {
        int addr = (w < 2) ? addrA : addrB;
        u32 lo = __builtin_amdgcn_ds_bpermute(addr, (int)pw[0][w & 1]);
        u32 hi = __builtin_amdgcn_ds_bpermute(addr, (int)pw[1][w & 1]);
        bw[w] = hiSel ? hi : lo;
      }
      bf16x8 pb = __builtin_bit_cast(bf16x8, bw);

      // O^T += V^T * P^T : accO[fd][r] = O^T[d = fd*16 + gl*4 + r][t = rl]
      __builtin_amdgcn_s_setprio(1);
#pragma unroll
      for (int fd = 0; fd < 8; ++fd) {
        const int d = fd*16 + rl;
        bf16x8 vf = *(const bf16x8*)(vl + d*64 + ((gl ^ ((d >> 1) & 3)) << 4));
        accO[fd] = __builtin_amdgcn_mfma_f32_16x16x32_bf16(vf, pb, accO[fd], 0, 0, 0);
      }
      __builtin_amdgcn_s_setprio(0);
    }

    __builtin_amdgcn_s_barrier();   // all waves done reading buf[it&1] before overwrite
  }

  const float inv = 1.0f / lrow;
  u16* outp = attout + (size_t)(b*TT + tg)*DIM + h*HD;
#pragma unroll
  for (int fd = 0; fd < 8; ++fd) {
    ushort4 o;
    o.x = f2bf(accO[fd][0] * inv);
    o.y = f2bf(accO[fd][1] * inv);
    o.z = f2bf(accO[fd][2] * inv);
    o.w = f2bf(accO[fd][3] * inv);
    *(ushort4*)(outp + fd*16 + gl*4) = o;
  }
}

// ---------------- launch ----------------
extern "C" void kernel_launch(void* const* d_in, const int* in_sizes, int n_in,
                              void* d_out, int out_size, void* d_ws, size_t ws_size,
                              hipStream_t stream) {
  const float* x    = (const float*)d_in[0];
  const float* Wqkv = (const float*)d_in[1];
  const float* bqkv = (const float*)d_in[2];
  const float* Wout = (const float*)d_in[3];
  const float* bout = (const float*)d_in[4];

  char* ws = (char*)d_ws;
  u16* xb    = (u16*)(ws);
  u16* wqb   = (u16*)(ws + 33554432);
  u16* qkvb  = (u16*)(ws + 33554432 + 9437184);
  u16* vtb   = (u16*)(ws + 33554432 + 9437184 + 37748736);
  u16* attb  = xb;     // x_bf16 dead after GEMM1
  u16* woutb = wqb;    // Wqkv_bf16 dead after GEMM1

  cvt_f32_bf16<<<2048, 256, 0, stream>>>(x,    xb,  NROW*DIM/4);
  cvt_f32_bf16<<<2048, 256, 0, stream>>>(Wqkv, wqb, QKVD*DIM/4);

  dim3 g1(NROW/128, QKVD/128);
  gemm_nt<true, true><<<g1, 256, 0, stream>>>(xb, wqb, bqkv, qkvb, vtb, DIM, QKVD);

  cvt_f32_bf16<<<2048, 256, 0, stream>>>(Wout, woutb, DIM*DIM/4);

  dim3 ga(TT/64, BB*NH);
  mqa_attn<<<ga, 256, 0, stream>>>(qkvb, vtb, attb);

  dim3 g2(NROW/128, DIM/128);
  gemm_nt<false, false><<<g2, 256, 0, stream>>>(attb, woutb, bout, d_out, nullptr, DIM, DIM);
}